// Round 21
// baseline (46.779 us; speedup 1.0000x reference)
//
#include <hip/hip_runtime.h>

// SSIM loss, 7x7 window, VALID, (64,1,512,512) fp32.
// R21 = R20 + 2-row batched LDS: slot entry = float4 {x_r,y_r,x_r+1,y_r+1}.
// Per 2 output rows: 7x ds_read_b128 + 1-2 b128 writes (was 14x b64 + 2-4),
// b128 moves 85 B/cy vs ~68 (m134), iterations/wait-points halved.
// VGPR budget is free here: SH=64 grid gives only 4 waves/SIMD, so <=128
// VGPR costs nothing (R13's VGPR failure was at the 8-wave/SIMD grid).
// Keeps: pk-f32 channel math (VALU 33->24us, R20-verified), read-early
// dual-slot, depth-2 parity prefetch, barrier-free wave-private strips.

constexpr int B  = 64;
constexpr int H  = 512, W = 512;
constexpr int OH = H - 6, OW = W - 6;     // 506
constexpr int CW = 64;                    // output cols per wave
constexpr int BW_ = 4 * CW;               // output cols per block (256)
constexpr int SH = 64;                    // output rows per block

typedef float f2 __attribute__((ext_vector_type(2)));
typedef float f4 __attribute__((ext_vector_type(4)));

__global__ __launch_bounds__(256)
void ssim_main(const float* __restrict__ X, const float* __restrict__ Y,
               const float* __restrict__ DR, float* __restrict__ partials)
{
    const int tid  = threadIdx.x;
    const int wid  = tid >> 6;
    const int lane = tid & 63;
    const int c0   = blockIdx.x * BW_ + wid * CW;   // wave-private strip
    const int r0   = blockIdx.y * SH;
    const int b    = blockIdx.z;

    const int out_rows = min(SH, OH - r0);
    const int rows_in  = out_rows + 6;       // 70 or 64 — always EVEN

    const float d  = DR[b];
    const float C1 = (0.01f * d) * (0.01f * d);
    const float C2 = (0.03f * d) * (0.03f * d);
    const float c1s = 2401.0f * C1;          // 49^2 * C1
    const float c2s = 2352.0f * C2;          // 48*49 * C2

    const float* __restrict__ Xb = X + (size_t)b * H * W;
    const float* __restrict__ Yb = Y + (size_t)b * H * W;

    unsigned off  = (unsigned)(r0 * W + c0 + lane);
    unsigned hoff = (unsigned)(r0 * W + min(c0 + CW + lane, W - 1));

    const bool colvalid = (c0 + lane) < OW;
    const bool is_halo  = lane < 6;

    // wave-private dual slots; entry = {x_r, y_r, x_{r+1}, y_{r+1}} per col
    __shared__ f4 rb[4][2][CW + 8];

    // vertical state: packed P=(sx,sy), Q=(sxx,syy); scalar sxy
    f2 bP[7], bQ[7];
    float bxy[7];
    f2 P = {0.f, 0.f}, Q = {0.f, 0.f};
    float vsxy = 0.f;
#pragma unroll
    for (int i = 0; i < 7; ++i) { bP[i] = P; bQ[i] = Q; bxy[i] = 0.f; }

    float acc = 0.f;

    // parity prefetch sets (each holds a 2-row pair, staged 2 iters later)
    f4 preA, preB;
    f4 prehA = {0.f,0.f,0.f,0.f}, prehB = {0.f,0.f,0.f,0.f};

    // ---- prologue: rows 0,1 -> slot0; rows 2,3 -> preA; rows 4,5 -> preB
    {
        f4 s, sh = {0.f,0.f,0.f,0.f};
        s.x = Xb[off]; s.y = Yb[off]; s.z = Xb[off+W]; s.w = Yb[off+W];
        if (is_halo) { sh.x = Xb[hoff]; sh.y = Yb[hoff];
                       sh.z = Xb[hoff+W]; sh.w = Yb[hoff+W]; }
        off += 2*W; hoff += 2*W;
        preA.x = Xb[off]; preA.y = Yb[off];
        preA.z = Xb[off+W]; preA.w = Yb[off+W];
        if (is_halo) { prehA.x = Xb[hoff]; prehA.y = Yb[hoff];
                       prehA.z = Xb[hoff+W]; prehA.w = Yb[hoff+W]; }
        off += 2*W; hoff += 2*W;
        preB.x = Xb[off]; preB.y = Yb[off];
        preB.z = Xb[off+W]; preB.w = Yb[off+W];
        if (is_halo) { prehB.x = Xb[hoff]; prehB.y = Yb[hoff];
                       prehB.z = Xb[hoff+W]; prehB.w = Yb[hoff+W]; }
        off += 2*W; hoff += 2*W;

        rb[wid][0][lane] = s;
        if (is_halo) rb[wid][0][CW + lane] = sh;
    }

    for (int kk = 0; kk < 42; kk += 14) {
#pragma unroll
        for (int p = 0; p < 14; ++p) {
            const int k = kk + p;
            const int r = 2 * k;               // this iter: rows r, r+1
            if (r < rows_in) {                 // block-uniform
                f4* const rslot = rb[wid][p & 1];        // holds rows r,r+1
                f4* const wslot = rb[wid][(p & 1) ^ 1];  // rows r+2,r+3 dest
                f4& pr = (p & 1) ? preB : preA;          // pair(r+2,r+3)
                f4& ph = (p & 1) ? prehB : prehA;

                // 1) tap reads (staged a full iteration ago)
                const f4 t0 = rslot[lane+0], t1 = rslot[lane+1],
                         t2 = rslot[lane+2], t3 = rslot[lane+3],
                         t4 = rslot[lane+4], t5 = rslot[lane+5],
                         t6 = rslot[lane+6];

                // 2) stage rows r+2,r+3 ; 3) refill this parity set with
                //    rows r+6,r+7 (consumed 2 iterations from now)
                if (r + 2 < rows_in) {
                    wslot[lane] = pr;
                    if (is_halo) wslot[CW + lane] = ph;
                    if (r + 6 < rows_in) {
                        pr.x = Xb[off]; pr.y = Yb[off];
                        pr.z = Xb[off+W]; pr.w = Yb[off+W];
                        if (is_halo) { ph.x = Xb[hoff]; ph.y = Yb[hoff];
                                       ph.z = Xb[hoff+W]; ph.w = Yb[hoff+W]; }
                        off += 2*W; hoff += 2*W;
                    }
                }

                // 4) compute rows r (lo pairs) and r+1 (hi pairs), pk-f32
                const f2 a0={t0.x,t0.y}, a1={t1.x,t1.y}, a2={t2.x,t2.y},
                         a3={t3.x,t3.y}, a4={t4.x,t4.y}, a5={t5.x,t5.y},
                         a6={t6.x,t6.y};
                const f2 b0={t0.z,t0.w}, b1={t1.z,t1.w}, b2={t2.z,t2.w},
                         b3={t3.z,t3.w}, b4={t4.z,t4.w}, b5={t5.z,t5.w},
                         b6={t6.z,t6.w};

                const f2 s2A = ((a0+a1)+(a2+a3)) + ((a4+a5)+a6);
                f2 q2A = a0*a0;
                q2A = __builtin_elementwise_fma(a1,a1,q2A);
                q2A = __builtin_elementwise_fma(a2,a2,q2A);
                q2A = __builtin_elementwise_fma(a3,a3,q2A);
                q2A = __builtin_elementwise_fma(a4,a4,q2A);
                q2A = __builtin_elementwise_fma(a5,a5,q2A);
                q2A = __builtin_elementwise_fma(a6,a6,q2A);
                float hxyA = a0.x*a0.y;
                hxyA = fmaf(a1.x,a1.y,hxyA); hxyA = fmaf(a2.x,a2.y,hxyA);
                hxyA = fmaf(a3.x,a3.y,hxyA); hxyA = fmaf(a4.x,a4.y,hxyA);
                hxyA = fmaf(a5.x,a5.y,hxyA); hxyA = fmaf(a6.x,a6.y,hxyA);

                const f2 s2B = ((b0+b1)+(b2+b3)) + ((b4+b5)+b6);
                f2 q2B = b0*b0;
                q2B = __builtin_elementwise_fma(b1,b1,q2B);
                q2B = __builtin_elementwise_fma(b2,b2,q2B);
                q2B = __builtin_elementwise_fma(b3,b3,q2B);
                q2B = __builtin_elementwise_fma(b4,b4,q2B);
                q2B = __builtin_elementwise_fma(b5,b5,q2B);
                q2B = __builtin_elementwise_fma(b6,b6,q2B);
                float hxyB = b0.x*b0.y;
                hxyB = fmaf(b1.x,b1.y,hxyB); hxyB = fmaf(b2.x,b2.y,hxyB);
                hxyB = fmaf(b3.x,b3.y,hxyB); hxyB = fmaf(b4.x,b4.y,hxyB);
                hxyB = fmaf(b5.x,b5.y,hxyB); hxyB = fmaf(b6.x,b6.y,hxyB);

                // vertical circular slots for rows r, r+1 (static)
                constexpr int s7a[14] = {0,2,4,6,1,3,5,0,2,4,6,1,3,5};
                constexpr int s7b[14] = {1,3,5,0,2,4,6,1,3,5,0,2,4,6};
                const bool emit = (r >= 6) && colvalid;

                {   const int sp = s7a[p];
                    P += s2A - bP[sp];     bP[sp] = s2A;
                    Q += q2A - bQ[sp];     bQ[sp] = q2A;
                    vsxy += hxyA - bxy[sp]; bxy[sp] = hxyA;
                }
                if (emit) {
                    const float vsx = P.x, vsy = P.y;
                    const float p1 = vsx * vsy;
                    const float u1 = fmaf(2.f, p1, c1s);
                    const float qv = fmaf(49.f, vsxy, -p1);
                    const float u2 = fmaf(2.f, qv, c2s);
                    const float n2 = fmaf(vsy, vsy, vsx * vsx);
                    const float d1 = n2 + c1s;
                    const float d2 = fmaf(49.f, Q.x + Q.y, c2s) - n2;
                    const float den = d1 * d2;
                    float rc = __builtin_amdgcn_rcpf(den);
                    rc = rc * (2.f - den * rc);
                    acc = fmaf(u1 * u2, rc, acc);
                }
                {   const int sp = s7b[p];
                    P += s2B - bP[sp];     bP[sp] = s2B;
                    Q += q2B - bQ[sp];     bQ[sp] = q2B;
                    vsxy += hxyB - bxy[sp]; bxy[sp] = hxyB;
                }
                if (emit) {                    // r+1 >= 7 iff r >= 6
                    const float vsx = P.x, vsy = P.y;
                    const float p1 = vsx * vsy;
                    const float u1 = fmaf(2.f, p1, c1s);
                    const float qv = fmaf(49.f, vsxy, -p1);
                    const float u2 = fmaf(2.f, qv, c2s);
                    const float n2 = fmaf(vsy, vsy, vsx * vsx);
                    const float d1 = n2 + c1s;
                    const float d2 = fmaf(49.f, Q.x + Q.y, c2s) - n2;
                    const float den = d1 * d2;
                    float rc = __builtin_amdgcn_rcpf(den);
                    rc = rc * (2.f - den * rc);
                    acc = fmaf(u1 * u2, rc, acc);
                }
            }
        }
    }

    // block reduction: wave shfl, then cross-wave via LDS (single barrier)
    float s = acc;
#pragma unroll
    for (int o = 32; o; o >>= 1) s += __shfl_down(s, o, 64);
    __shared__ float wsum[4];
    if (lane == 0) wsum[wid] = s;
    __syncthreads();
    if (tid == 0) {
        const int bid = (blockIdx.z * gridDim.y + blockIdx.y) * gridDim.x + blockIdx.x;
        partials[bid] = wsum[0] + wsum[1] + wsum[2] + wsum[3];
    }
}

__global__ __launch_bounds__(256)
void ssim_final(const float* __restrict__ partials, int n,
                float* __restrict__ out, float inv_count)
{
    const int tid = threadIdx.x;
    float s = 0.f;
    for (int i = tid; i < n; i += 256) s += partials[i];
#pragma unroll
    for (int o = 32; o; o >>= 1) s += __shfl_down(s, o, 64);
    __shared__ float wsum[4];
    if ((tid & 63) == 0) wsum[tid >> 6] = s;
    __syncthreads();
    if (tid == 0) out[0] = 1.0f - (wsum[0] + wsum[1] + wsum[2] + wsum[3]) * inv_count;
}

extern "C" void kernel_launch(void* const* d_in, const int* in_sizes, int n_in,
                              void* d_out, int out_size, void* d_ws, size_t ws_size,
                              hipStream_t stream)
{
    const float* X  = (const float*)d_in[0];
    const float* Y  = (const float*)d_in[1];
    const float* DR = (const float*)d_in[2];
    float* out      = (float*)d_out;
    float* partials = (float*)d_ws;

    const int gx = (OW + BW_ - 1) / BW_; // 2
    const int gy = (OH + SH - 1) / SH;   // 8
    dim3 grid(gx, gy, B);                // 1024 blocks, every partial slot written
    ssim_main<<<grid, 256, 0, stream>>>(X, Y, DR, partials);

    const int n = gx * gy * B;           // 1024
    const float inv_count = 1.0f / (float)((long)B * OH * OW);
    ssim_final<<<1, 256, 0, stream>>>(partials, n, out, inv_count);
}